// Round 3
// baseline (344.605 us; speedup 1.0000x reference)
//
#include <hip/hip_runtime.h>
#include <math.h>

#define EMBED 1024
#define SEQ   2048
#define HEAD  64
#define NROW  8192   /* BATCH*SEQ */

// ---------------------------------------------------------------------------
// Round 1: correctness-first all-f32 baseline (no MFMA).
//   K1 qkv_proj: P[kz][which][row][h] = partial x@W^T, K-split=2 (balance).
//   K2 attn:     flash-style causal attention, f32 VALU,
//                lane=(kk,dg) decomposition keeps Q + acc in registers.
// Precision note: bf16 MFMA on the QK path fails the 2%-of-max threshold
// (logit std ~105, bf16 noise ~0.5 in the exponent) -> f32 now, split-bf16
// MFMA later.
// ---------------------------------------------------------------------------

__global__ __launch_bounds__(256, 4)
void qkv_proj(const float* __restrict__ x,
              const float* __restrict__ Wq,
              const float* __restrict__ Wk,
              const float* __restrict__ Wv,
              float* __restrict__ P)
{
    const int bx    = blockIdx.x;   // 0..127 row tile (64 rows)
    const int which = blockIdx.y;   // 0=Q 1=K 2=V
    const int kz    = blockIdx.z;   // 0..1 K-split halves
    const int tid   = threadIdx.x;
    const int tx = tid & 15, ty = tid >> 4;

    const float* W = (which == 0) ? Wq : (which == 1) ? Wk : Wv;
    const int row0 = bx * 64;
    const int kbeg = kz * 512;

    // stride 36 floats: 144B rows -> 16B-aligned float4, <=2-way bank alias
    __shared__ float xs [64 * 36];
    __shared__ float wsm[64 * 36];

    float acc[4][4];
#pragma unroll
    for (int i = 0; i < 4; ++i)
#pragma unroll
        for (int j = 0; j < 4; ++j) acc[i][j] = 0.f;

    for (int ks = 0; ks < 16; ++ks) {          // 16 steps of K=32
        const int k0 = kbeg + ks * 32;
        __syncthreads();
#pragma unroll
        for (int pp = 0; pp < 2; ++pp) {       // 512 float4 each for x and W
            const int idx = pp * 256 + tid;    // 0..511
            const int r  = idx >> 3;           // 0..63
            const int c4 = idx & 7;            // 0..7 (float4 within 32)
            float4 xv = *(const float4*)&x[(size_t)(row0 + r) * EMBED + k0 + c4 * 4];
            *(float4*)&xs[r * 36 + c4 * 4] = xv;
            float4 wv = *(const float4*)&W[(size_t)r * EMBED + k0 + c4 * 4];
            *(float4*)&wsm[r * 36 + c4 * 4] = wv;
        }
        __syncthreads();
#pragma unroll
        for (int kk4 = 0; kk4 < 8; ++kk4) {
            float4 a[4], b[4];
#pragma unroll
            for (int i = 0; i < 4; ++i)
                a[i] = *(const float4*)&xs[(ty * 4 + i) * 36 + kk4 * 4];
#pragma unroll
            for (int j = 0; j < 4; ++j)
                b[j] = *(const float4*)&wsm[(tx + 16 * j) * 36 + kk4 * 4];
#pragma unroll
            for (int i = 0; i < 4; ++i)
#pragma unroll
                for (int j = 0; j < 4; ++j)
                    acc[i][j] += a[i].x * b[j].x + a[i].y * b[j].y
                               + a[i].z * b[j].z + a[i].w * b[j].w;
        }
    }

    float* Pbase = P + (size_t)(kz * 3 + which) * NROW * HEAD;
#pragma unroll
    for (int i = 0; i < 4; ++i)
#pragma unroll
        for (int j = 0; j < 4; ++j)
            Pbase[(size_t)(row0 + ty * 4 + i) * HEAD + tx + 16 * j] = acc[i][j];
}

// ---------------------------------------------------------------------------
// Attention: 16 q-rows per block, 4 waves x 4 rows, 64-key LDS tiles.
// lane = dg*16 + kk ; kk = key mod 16, dg = 16-dim group AND j-slot (key/16).
// ---------------------------------------------------------------------------

__global__ __launch_bounds__(256, 2)
void attn(const float* __restrict__ P, float* __restrict__ out)
{
    const int bi = blockIdx.x;  // 0..511
    int b, t16;
    if (bi < 256) { b = bi >> 7;            t16 = bi & 127; }
    else          { int j = bi - 256; b = 2 + (j >> 7); t16 = 127 - (j & 127); }
    const int q0 = t16 * 16;

    const int tid  = threadIdx.x;
    const int w    = tid >> 6;      // wave 0..3
    const int lane = tid & 63;
    const int kk   = lane & 15;
    const int dg   = lane >> 4;
    const int sw   = kk & 7;        // LDS chunk swizzle key

    const float* Pq0 = P + (size_t)0 * NROW * HEAD;
    const float* Pk0 = P + (size_t)1 * NROW * HEAD;
    const float* Pv0 = P + (size_t)2 * NROW * HEAD;
    const float* Pq1 = P + (size_t)3 * NROW * HEAD;
    const float* Pk1 = P + (size_t)4 * NROW * HEAD;
    const float* Pv1 = P + (size_t)5 * NROW * HEAD;

    __shared__ float Ks[64 * 64];
    __shared__ float Vs[64 * 64];
    __shared__ float ps[4][4][64];   // [wave][row][key]
    __shared__ float obuf[16 * 64];

    // ---- Q into registers (sum K-split partials, fold in the *32 scale) ----
    float4 qv[4][4];
    int qrow[4];
#pragma unroll
    for (int r = 0; r < 4; ++r) {
        qrow[r] = q0 + 4 * w + r;
        const size_t base = ((size_t)b * SEQ + qrow[r]) * HEAD + dg * 16;
#pragma unroll
        for (int c = 0; c < 4; ++c) {
            float4 a0 = *(const float4*)&Pq0[base + c * 4];
            float4 a1 = *(const float4*)&Pq1[base + c * 4];
            qv[r][c] = make_float4(32.f * (a0.x + a1.x), 32.f * (a0.y + a1.y),
                                   32.f * (a0.z + a1.z), 32.f * (a0.w + a1.w));
        }
    }

    float m[4], l[4];
    float4 po[4][4];
#pragma unroll
    for (int r = 0; r < 4; ++r) {
        m[r] = -1e30f; l[r] = 0.f;
#pragma unroll
        for (int c = 0; c < 4; ++c) po[r][c] = make_float4(0.f, 0.f, 0.f, 0.f);
    }

    const int ntiles = q0 / 64 + 1;
    for (int kt = 0; kt < ntiles; ++kt) {
        const int kbase = kt * 64;
        __syncthreads();
        // ---- stage K,V tile (sum partials), chunk-swizzled rows ----
#pragma unroll
        for (int pp = 0; pp < 4; ++pp) {
            const int idx = pp * 256 + tid;   // 0..1023
            const int key = idx >> 4;
            const int c4  = idx & 15;
            const int cc  = c4 ^ (key & 7);
            const size_t g = ((size_t)b * SEQ + kbase + key) * HEAD + c4 * 4;
            float4 k0v = *(const float4*)&Pk0[g];
            float4 k1v = *(const float4*)&Pk1[g];
            *(float4*)&Ks[key * 64 + cc * 4] =
                make_float4(k0v.x + k1v.x, k0v.y + k1v.y, k0v.z + k1v.z, k0v.w + k1v.w);
            float4 v0v = *(const float4*)&Pv0[g];
            float4 v1v = *(const float4*)&Pv1[g];
            *(float4*)&Vs[key * 64 + cc * 4] =
                make_float4(v0v.x + v1v.x, v0v.y + v1v.y, v0v.z + v1v.z, v0v.w + v1v.w);
        }
        __syncthreads();

        // ---- QK^T : s[r][j] = 32*Q[row_r] . K[kk+16j]  (partial over dg dims)
        float s[4][4];
#pragma unroll
        for (int j = 0; j < 4; ++j) {
            const int krow = (kk + 16 * j) * 64;
            float4 kf[4];
#pragma unroll
            for (int q = 0; q < 4; ++q)
                kf[q] = *(const float4*)&Ks[krow + ((dg * 4 + q) ^ sw) * 4];
#pragma unroll
            for (int r = 0; r < 4; ++r) {
                float a = 0.f;
#pragma unroll
                for (int q = 0; q < 4; ++q)
                    a += qv[r][q].x * kf[q].x + qv[r][q].y * kf[q].y
                       + qv[r][q].z * kf[q].z + qv[r][q].w * kf[q].w;
                s[r][j] = a;
            }
        }
        // reduce partial dots over the 4 dg lanes (lane bits 4,5)
#pragma unroll
        for (int r = 0; r < 4; ++r)
#pragma unroll
            for (int j = 0; j < 4; ++j) {
                float v = s[r][j];
                v += __shfl_xor(v, 16);
                v += __shfl_xor(v, 32);
                s[r][j] = v;
            }

        // ---- online softmax (lane == key within tile, since key=kk+16*dg) --
        const int keyg = kbase + lane;
#pragma unroll
        for (int r = 0; r < 4; ++r) {
            float sl = (dg == 0) ? s[r][0] : (dg == 1) ? s[r][1]
                     : (dg == 2) ? s[r][2] : s[r][3];
            float sv = (keyg <= qrow[r]) ? sl : -1e30f;
            float tmax = sv;
#pragma unroll
            for (int off = 1; off < 64; off <<= 1)
                tmax = fmaxf(tmax, __shfl_xor(tmax, off));
            const float mnew = fmaxf(m[r], tmax);
            const float fac  = __expf(m[r] - mnew);
            const float pv   = __expf(sv - mnew);
            float psum = pv;
#pragma unroll
            for (int off = 1; off < 64; off <<= 1)
                psum += __shfl_xor(psum, off);
            l[r] = l[r] * fac + psum;
            m[r] = mnew;
#pragma unroll
            for (int c = 0; c < 4; ++c) {
                po[r][c].x *= fac; po[r][c].y *= fac;
                po[r][c].z *= fac; po[r][c].w *= fac;
            }
            ps[w][r][lane] = pv;
        }
        __syncthreads();   // also orders ps writes vs reads (cheap, safe)

        // ---- PV : po[r][q-chunk] += sum_j p[r][kk+16j] * V[kk+16j][dg dims]
#pragma unroll
        for (int j = 0; j < 4; ++j) {
            const int key  = kk + 16 * j;
            const int krow = key * 64;
            float4 vf[4];
#pragma unroll
            for (int q = 0; q < 4; ++q)
                vf[q] = *(const float4*)&Vs[krow + ((dg * 4 + q) ^ sw) * 4];
            float pj[4];
#pragma unroll
            for (int r = 0; r < 4; ++r) pj[r] = ps[w][r][key];
#pragma unroll
            for (int r = 0; r < 4; ++r)
#pragma unroll
                for (int q = 0; q < 4; ++q) {
                    po[r][q].x += pj[r] * vf[q].x;
                    po[r][q].y += pj[r] * vf[q].y;
                    po[r][q].z += pj[r] * vf[q].z;
                    po[r][q].w += pj[r] * vf[q].w;
                }
        }
    }

    // ---- reduce po across the 16 kk lanes (lane bits 0..3) ----
#pragma unroll
    for (int r = 0; r < 4; ++r)
#pragma unroll
        for (int q = 0; q < 4; ++q) {
            float4 v = po[r][q];
#pragma unroll
            for (int off = 1; off < 16; off <<= 1) {
                v.x += __shfl_xor(v.x, off);
                v.y += __shfl_xor(v.y, off);
                v.z += __shfl_xor(v.z, off);
                v.w += __shfl_xor(v.w, off);
            }
            po[r][q] = v;
        }

    if (kk == 0) {
#pragma unroll
        for (int r = 0; r < 4; ++r) {
            const float inv = 1.0f / l[r];
#pragma unroll
            for (int q = 0; q < 4; ++q) {
                float4 v = po[r][q];
                v.x *= inv; v.y *= inv; v.z *= inv; v.w *= inv;
                *(float4*)&obuf[(4 * w + r) * 64 + dg * 16 + q * 4] = v;
            }
        }
    }
    __syncthreads();

    const int row = tid >> 4, c4 = tid & 15;
    *(float4*)&out[((size_t)b * SEQ + q0 + row) * HEAD + c4 * 4] =
        *(const float4*)&obuf[row * 64 + c4 * 4];
}

// ---------------------------------------------------------------------------

extern "C" void kernel_launch(void* const* d_in, const int* in_sizes, int n_in,
                              void* d_out, int out_size, void* d_ws, size_t ws_size,
                              hipStream_t stream)
{
    // setup_inputs order: x, Wk, Wq, Wv
    const float* x  = (const float*)d_in[0];
    const float* Wk = (const float*)d_in[1];
    const float* Wq = (const float*)d_in[2];
    const float* Wv = (const float*)d_in[3];
    float* P = (float*)d_ws;              // 2*3*8192*64 f32 = 12.6 MB partials

    qkv_proj<<<dim3(128, 3, 2), 256, 0, stream>>>(x, Wq, Wk, Wv, P);
    attn<<<dim3(512), 256, 0, stream>>>(P, (float*)d_out);
}

// Round 4
// 343.664 us; speedup vs baseline: 1.0027x; 1.0027x over previous
//
#include <hip/hip_runtime.h>
#include <math.h>

#define EMBED 1024
#define SEQ   2048
#define HEAD  64
#define NROW  8192   /* BATCH*SEQ */

// ---------------------------------------------------------------------------
// Round 1: correctness-first all-f32 baseline (no MFMA).
//   K1 qkv_proj: P[kz][which][row][h] = partial x@W^T, K-split=2 (balance).
//   K2 attn:     flash-style causal attention, f32 VALU,
//                lane=(kk,dg) decomposition keeps Q + acc in registers.
// Precision note: bf16 MFMA on the QK path fails the 2%-of-max threshold
// (logit std ~105, bf16 noise ~0.5 in the exponent) -> f32 now, split-bf16
// MFMA later.
// ---------------------------------------------------------------------------

__global__ __launch_bounds__(256, 4)
void qkv_proj(const float* __restrict__ x,
              const float* __restrict__ Wq,
              const float* __restrict__ Wk,
              const float* __restrict__ Wv,
              float* __restrict__ P)
{
    const int bx    = blockIdx.x;   // 0..127 row tile (64 rows)
    const int which = blockIdx.y;   // 0=Q 1=K 2=V
    const int kz    = blockIdx.z;   // 0..1 K-split halves
    const int tid   = threadIdx.x;
    const int tx = tid & 15, ty = tid >> 4;

    const float* W = (which == 0) ? Wq : (which == 1) ? Wk : Wv;
    const int row0 = bx * 64;
    const int kbeg = kz * 512;

    // stride 36 floats: 144B rows -> 16B-aligned float4, <=2-way bank alias
    __shared__ float xs [64 * 36];
    __shared__ float wsm[64 * 36];

    float acc[4][4];
#pragma unroll
    for (int i = 0; i < 4; ++i)
#pragma unroll
        for (int j = 0; j < 4; ++j) acc[i][j] = 0.f;

    for (int ks = 0; ks < 16; ++ks) {          // 16 steps of K=32
        const int k0 = kbeg + ks * 32;
        __syncthreads();
#pragma unroll
        for (int pp = 0; pp < 2; ++pp) {       // 512 float4 each for x and W
            const int idx = pp * 256 + tid;    // 0..511
            const int r  = idx >> 3;           // 0..63
            const int c4 = idx & 7;            // 0..7 (float4 within 32)
            float4 xv = *(const float4*)&x[(size_t)(row0 + r) * EMBED + k0 + c4 * 4];
            *(float4*)&xs[r * 36 + c4 * 4] = xv;
            float4 wv = *(const float4*)&W[(size_t)r * EMBED + k0 + c4 * 4];
            *(float4*)&wsm[r * 36 + c4 * 4] = wv;
        }
        __syncthreads();
#pragma unroll
        for (int kk4 = 0; kk4 < 8; ++kk4) {
            float4 a[4], b[4];
#pragma unroll
            for (int i = 0; i < 4; ++i)
                a[i] = *(const float4*)&xs[(ty * 4 + i) * 36 + kk4 * 4];
#pragma unroll
            for (int j = 0; j < 4; ++j)
                b[j] = *(const float4*)&wsm[(tx + 16 * j) * 36 + kk4 * 4];
#pragma unroll
            for (int i = 0; i < 4; ++i)
#pragma unroll
                for (int j = 0; j < 4; ++j)
                    acc[i][j] += a[i].x * b[j].x + a[i].y * b[j].y
                               + a[i].z * b[j].z + a[i].w * b[j].w;
        }
    }

    float* Pbase = P + (size_t)(kz * 3 + which) * NROW * HEAD;
#pragma unroll
    for (int i = 0; i < 4; ++i)
#pragma unroll
        for (int j = 0; j < 4; ++j)
            Pbase[(size_t)(row0 + ty * 4 + i) * HEAD + tx + 16 * j] = acc[i][j];
}

// ---------------------------------------------------------------------------
// Attention: 16 q-rows per block, 4 waves x 4 rows, 64-key LDS tiles.
// lane = dg*16 + kk ; kk = key mod 16, dg = 16-dim group AND j-slot (key/16).
// ---------------------------------------------------------------------------

__global__ __launch_bounds__(256, 2)
void attn(const float* __restrict__ P, float* __restrict__ out)
{
    const int bi = blockIdx.x;  // 0..511
    int b, t16;
    if (bi < 256) { b = bi >> 7;            t16 = bi & 127; }
    else          { int j = bi - 256; b = 2 + (j >> 7); t16 = 127 - (j & 127); }
    const int q0 = t16 * 16;

    const int tid  = threadIdx.x;
    const int w    = tid >> 6;      // wave 0..3
    const int lane = tid & 63;
    const int kk   = lane & 15;
    const int dg   = lane >> 4;
    const int sw   = kk & 7;        // LDS chunk swizzle key

    const float* Pq0 = P + (size_t)0 * NROW * HEAD;
    const float* Pk0 = P + (size_t)1 * NROW * HEAD;
    const float* Pv0 = P + (size_t)2 * NROW * HEAD;
    const float* Pq1 = P + (size_t)3 * NROW * HEAD;
    const float* Pk1 = P + (size_t)4 * NROW * HEAD;
    const float* Pv1 = P + (size_t)5 * NROW * HEAD;

    __shared__ float Ks[64 * 64];
    __shared__ float Vs[64 * 64];
    __shared__ float ps[4][4][64];   // [wave][row][key]
    __shared__ float obuf[16 * 64];

    // ---- Q into registers (sum K-split partials, fold in the *32 scale) ----
    float4 qv[4][4];
    int qrow[4];
#pragma unroll
    for (int r = 0; r < 4; ++r) {
        qrow[r] = q0 + 4 * w + r;
        const size_t base = ((size_t)b * SEQ + qrow[r]) * HEAD + dg * 16;
#pragma unroll
        for (int c = 0; c < 4; ++c) {
            float4 a0 = *(const float4*)&Pq0[base + c * 4];
            float4 a1 = *(const float4*)&Pq1[base + c * 4];
            qv[r][c] = make_float4(32.f * (a0.x + a1.x), 32.f * (a0.y + a1.y),
                                   32.f * (a0.z + a1.z), 32.f * (a0.w + a1.w));
        }
    }

    float m[4], l[4];
    float4 po[4][4];
#pragma unroll
    for (int r = 0; r < 4; ++r) {
        m[r] = -1e30f; l[r] = 0.f;
#pragma unroll
        for (int c = 0; c < 4; ++c) po[r][c] = make_float4(0.f, 0.f, 0.f, 0.f);
    }

    const int ntiles = q0 / 64 + 1;
    for (int kt = 0; kt < ntiles; ++kt) {
        const int kbase = kt * 64;
        __syncthreads();
        // ---- stage K,V tile (sum partials), chunk-swizzled rows ----
#pragma unroll
        for (int pp = 0; pp < 4; ++pp) {
            const int idx = pp * 256 + tid;   // 0..1023
            const int key = idx >> 4;
            const int c4  = idx & 15;
            const int cc  = c4 ^ (key & 7);
            const size_t g = ((size_t)b * SEQ + kbase + key) * HEAD + c4 * 4;
            float4 k0v = *(const float4*)&Pk0[g];
            float4 k1v = *(const float4*)&Pk1[g];
            *(float4*)&Ks[key * 64 + cc * 4] =
                make_float4(k0v.x + k1v.x, k0v.y + k1v.y, k0v.z + k1v.z, k0v.w + k1v.w);
            float4 v0v = *(const float4*)&Pv0[g];
            float4 v1v = *(const float4*)&Pv1[g];
            *(float4*)&Vs[key * 64 + cc * 4] =
                make_float4(v0v.x + v1v.x, v0v.y + v1v.y, v0v.z + v1v.z, v0v.w + v1v.w);
        }
        __syncthreads();

        // ---- QK^T : s[r][j] = 32*Q[row_r] . K[kk+16j]  (partial over dg dims)
        float s[4][4];
#pragma unroll
        for (int j = 0; j < 4; ++j) {
            const int krow = (kk + 16 * j) * 64;
            float4 kf[4];
#pragma unroll
            for (int q = 0; q < 4; ++q)
                kf[q] = *(const float4*)&Ks[krow + ((dg * 4 + q) ^ sw) * 4];
#pragma unroll
            for (int r = 0; r < 4; ++r) {
                float a = 0.f;
#pragma unroll
                for (int q = 0; q < 4; ++q)
                    a += qv[r][q].x * kf[q].x + qv[r][q].y * kf[q].y
                       + qv[r][q].z * kf[q].z + qv[r][q].w * kf[q].w;
                s[r][j] = a;
            }
        }
        // reduce partial dots over the 4 dg lanes (lane bits 4,5)
#pragma unroll
        for (int r = 0; r < 4; ++r)
#pragma unroll
            for (int j = 0; j < 4; ++j) {
                float v = s[r][j];
                v += __shfl_xor(v, 16);
                v += __shfl_xor(v, 32);
                s[r][j] = v;
            }

        // ---- online softmax (lane == key within tile, since key=kk+16*dg) --
        const int keyg = kbase + lane;
#pragma unroll
        for (int r = 0; r < 4; ++r) {
            float sl = (dg == 0) ? s[r][0] : (dg == 1) ? s[r][1]
                     : (dg == 2) ? s[r][2] : s[r][3];
            float sv = (keyg <= qrow[r]) ? sl : -1e30f;
            float tmax = sv;
#pragma unroll
            for (int off = 1; off < 64; off <<= 1)
                tmax = fmaxf(tmax, __shfl_xor(tmax, off));
            const float mnew = fmaxf(m[r], tmax);
            const float fac  = __expf(m[r] - mnew);
            const float pv   = __expf(sv - mnew);
            float psum = pv;
#pragma unroll
            for (int off = 1; off < 64; off <<= 1)
                psum += __shfl_xor(psum, off);
            l[r] = l[r] * fac + psum;
            m[r] = mnew;
#pragma unroll
            for (int c = 0; c < 4; ++c) {
                po[r][c].x *= fac; po[r][c].y *= fac;
                po[r][c].z *= fac; po[r][c].w *= fac;
            }
            ps[w][r][lane] = pv;
        }
        __syncthreads();   // also orders ps writes vs reads (cheap, safe)

        // ---- PV : po[r][q-chunk] += sum_j p[r][kk+16j] * V[kk+16j][dg dims]
#pragma unroll
        for (int j = 0; j < 4; ++j) {
            const int key  = kk + 16 * j;
            const int krow = key * 64;
            float4 vf[4];
#pragma unroll
            for (int q = 0; q < 4; ++q)
                vf[q] = *(const float4*)&Vs[krow + ((dg * 4 + q) ^ sw) * 4];
            float pj[4];
#pragma unroll
            for (int r = 0; r < 4; ++r) pj[r] = ps[w][r][key];
#pragma unroll
            for (int r = 0; r < 4; ++r)
#pragma unroll
                for (int q = 0; q < 4; ++q) {
                    po[r][q].x += pj[r] * vf[q].x;
                    po[r][q].y += pj[r] * vf[q].y;
                    po[r][q].z += pj[r] * vf[q].z;
                    po[r][q].w += pj[r] * vf[q].w;
                }
        }
    }

    // ---- reduce po across the 16 kk lanes (lane bits 0..3) ----
#pragma unroll
    for (int r = 0; r < 4; ++r)
#pragma unroll
        for (int q = 0; q < 4; ++q) {
            float4 v = po[r][q];
#pragma unroll
            for (int off = 1; off < 16; off <<= 1) {
                v.x += __shfl_xor(v.x, off);
                v.y += __shfl_xor(v.y, off);
                v.z += __shfl_xor(v.z, off);
                v.w += __shfl_xor(v.w, off);
            }
            po[r][q] = v;
        }

    if (kk == 0) {
#pragma unroll
        for (int r = 0; r < 4; ++r) {
            const float inv = 1.0f / l[r];
#pragma unroll
            for (int q = 0; q < 4; ++q) {
                float4 v = po[r][q];
                v.x *= inv; v.y *= inv; v.z *= inv; v.w *= inv;
                *(float4*)&obuf[(4 * w + r) * 64 + dg * 16 + q * 4] = v;
            }
        }
    }
    __syncthreads();

    const int row = tid >> 4, c4 = tid & 15;
    *(float4*)&out[((size_t)b * SEQ + q0 + row) * HEAD + c4 * 4] =
        *(const float4*)&obuf[row * 64 + c4 * 4];
}

// ---------------------------------------------------------------------------

extern "C" void kernel_launch(void* const* d_in, const int* in_sizes, int n_in,
                              void* d_out, int out_size, void* d_ws, size_t ws_size,
                              hipStream_t stream)
{
    // setup_inputs order: x, Wk, Wq, Wv
    const float* x  = (const float*)d_in[0];
    const float* Wk = (const float*)d_in[1];
    const float* Wq = (const float*)d_in[2];
    const float* Wv = (const float*)d_in[3];
    float* P = (float*)d_ws;              // 2*3*8192*64 f32 = 12.6 MB partials

    qkv_proj<<<dim3(128, 3, 2), 256, 0, stream>>>(x, Wq, Wk, Wv, P);
    attn<<<dim3(512), 256, 0, stream>>>(P, (float*)d_out);
}